// Round 7
// baseline (529.645 us; speedup 1.0000x reference)
//
#include <hip/hip_runtime.h>
#include <cstdint>
#include <cstddef>

#define NR 8192
#define DD 128
#define NSPLIT 8
#define GAT_ALPHA 0.2f

typedef short short8 __attribute__((ext_vector_type(8)));
typedef unsigned short ushort8 __attribute__((ext_vector_type(8)));
typedef float f32x4 __attribute__((ext_vector_type(4)));
typedef int i32x4 __attribute__((ext_vector_type(4)));

__device__ __forceinline__ unsigned short f2bf(float f){
  unsigned u = __float_as_uint(f);
  u += 0x7fffu + ((u >> 16) & 1u);           // RNE round to bf16
  return (unsigned short)(u >> 16);
}
__device__ __forceinline__ unsigned fenc(float f){   // monotone float->uint
  unsigned u = __float_as_uint(f);
  return (u & 0x80000000u) ? ~u : (u | 0x80000000u);
}
__device__ __forceinline__ float fdec(unsigned e){
  unsigned u = (e & 0x80000000u) ? (e ^ 0x80000000u) : ~e;
  return __uint_as_float(u);
}

// ---- k1: h = in@W (regs only), f1=h@a1, f2=h@a2, gmax=max(f2),
//          hTb = bf16(h)^T in K-blocked layout [r/64][c][r%64]
__global__ __launch_bounds__(256) void k_pre(
    const float* __restrict__ in, const float* __restrict__ W,
    const float* __restrict__ a,
    unsigned short* __restrict__ hTb, float* __restrict__ f1,
    float* __restrict__ f2, unsigned* __restrict__ gmax)
{
  __shared__ __align__(16) unsigned short sT[128][8];   // [col][row-in-block]
  const int tid = threadIdx.x;
  const int g = blockIdx.x * 256 + tid;
  const int r  = g >> 5;                    // row 0..8191 (8 rows per block)
  const int cg = g & 31;                    // col-quad
  const float4* inr = (const float4*)(in + (size_t)r * DD);
  const float4* W4  = (const float4*)W;
  float4 acc = make_float4(0.f, 0.f, 0.f, 0.f);
  #pragma unroll 4
  for (int k4 = 0; k4 < 32; ++k4){
    float4 iv = inr[k4];
    float4 wv;
    wv = W4[(k4*4+0)*32 + cg];
    acc.x = fmaf(iv.x, wv.x, acc.x); acc.y = fmaf(iv.x, wv.y, acc.y);
    acc.z = fmaf(iv.x, wv.z, acc.z); acc.w = fmaf(iv.x, wv.w, acc.w);
    wv = W4[(k4*4+1)*32 + cg];
    acc.x = fmaf(iv.y, wv.x, acc.x); acc.y = fmaf(iv.y, wv.y, acc.y);
    acc.z = fmaf(iv.y, wv.z, acc.z); acc.w = fmaf(iv.y, wv.w, acc.w);
    wv = W4[(k4*4+2)*32 + cg];
    acc.x = fmaf(iv.z, wv.x, acc.x); acc.y = fmaf(iv.z, wv.y, acc.y);
    acc.z = fmaf(iv.z, wv.z, acc.z); acc.w = fmaf(iv.z, wv.w, acc.w);
    wv = W4[(k4*4+3)*32 + cg];
    acc.x = fmaf(iv.w, wv.x, acc.x); acc.y = fmaf(iv.w, wv.y, acc.y);
    acc.z = fmaf(iv.w, wv.z, acc.z); acc.w = fmaf(iv.w, wv.w, acc.w);
  }
  const int c0 = cg * 4;
  float s1 = acc.x*a[c0] + acc.y*a[c0+1] + acc.z*a[c0+2] + acc.w*a[c0+3];
  float s2 = acc.x*a[128+c0] + acc.y*a[128+c0+1] + acc.z*a[128+c0+2] + acc.w*a[128+c0+3];
  #pragma unroll
  for (int off = 16; off; off >>= 1){
    s1 += __shfl_xor(s1, off, 64);
    s2 += __shfl_xor(s2, off, 64);
  }
  if ((tid & 31) == 0){
    f1[r] = s1; f2[r] = s2;
    atomicMax(gmax, fenc(s2));
  }
  const int rl = r & 7;
  sT[c0+0][rl] = f2bf(acc.x);
  sT[c0+1][rl] = f2bf(acc.y);
  sT[c0+2][rl] = f2bf(acc.z);
  sT[c0+3][rl] = f2bf(acc.w);
  __syncthreads();
  if (tid < 128){
    ushort8 v = *(const ushort8*)&sT[tid][0];
    const int r0 = blockIdx.x * 8;
    // blocked: hTb[(r0/64)*128 + col][r0%64 .. +8]
    *(ushort8*)(hTb + ((size_t)(r0 >> 6) * 128 + tid) * 64 + (r0 & 63)) = v;
  }
}

// ---- k2: masked-softmax-weighted GEMM — NO LDS, NO BARRIERS ---------------
// grid (8 ksplits, 128 rowblocks) x 256 thr (4 waves); wave owns 16 rows x 128 cols.
// B-fragments read directly from L1/L2-resident blocked hTb (coalesced dwordx4);
// adj via depth-2 register prefetch; per-wave pipeline, compiler-staged vmcnt.
__global__ __launch_bounds__(256, 3) void k_attn(
    const int* __restrict__ adj, const unsigned short* __restrict__ hTb,
    const float* __restrict__ f1, const float* __restrict__ f2,
    const unsigned* __restrict__ gmax,
    float* __restrict__ Opart, float* __restrict__ lpart)
{
  const int s    = blockIdx.x;        // ksplit 0..7  (1024 k each, 16 chunks)
  const int rb   = blockIdx.y;        // rowblock 0..127 (64 rows)
  const int tid  = threadIdx.x;
  const int w    = tid >> 6;          // wave 0..3
  const int lane = tid & 63;
  const int quad = lane >> 4;
  const int m    = lane & 15;
  const int i    = rb * 64 + w * 16 + m;    // this lane's P row
  const int k0   = s * 1024;

  const float F2MAX = fdec(*gmax);
  const float f1i = f1[i];
  const float mm = f1i + F2MAX;
  const float mi = fmaxf(mm, GAT_ALPHA * mm);  // lrelu(f1+maxf2) >= row max, exact bound
  const float L2E = 1.44269504089f;
  const float miL = mi * L2E;

  f32x4 acc[8];
  #pragma unroll
  for (int ct = 0; ct < 8; ++ct){ acc[ct][0]=0.f; acc[ct][1]=0.f; acc[ct][2]=0.f; acc[ct][3]=0.f; }
  float lp = 0.f;

  const int* arow = adj + (size_t)i * NR + k0 + quad * 8;
  // per-lane base into blocked hTb: kblock (s*16), col m, k-within-block quad*8
  const unsigned short* hb = hTb + ((size_t)(s * 16) * 128 + m) * 64 + quad * 8;

  i32x4 av[4], bv[4], nv[4];          // depth-2 rotating adj prefetch queue

  auto loadAdj = [&](int kc, i32x4* dst){
    const i32x4* p0 = (const i32x4*)(arow + kc * 64);
    #pragma unroll
    for (int ks = 0; ks < 2; ++ks){
      dst[2*ks]   = __builtin_nontemporal_load(p0 + ks*8);
      dst[2*ks+1] = __builtin_nontemporal_load(p0 + ks*8 + 1);
    }
  };

  loadAdj(0, av);
  loadAdj(1, bv);

  for (int kc = 0; kc < 16; ++kc){
    if (kc < 14) loadAdj(kc + 2, nv);       // depth-2 register prefetch

    // f2 for this chunk straight from global (4KB slice, L1-broadcast)
    const float4* f2g = (const float4*)(f2 + k0 + kc * 64);

    // P in A-frag layout: A[m=lane&15][k = ks*32 + quad*8 + j]
    short8 afr[2];
    #pragma unroll
    for (int ks = 0; ks < 2; ++ks){
      float4 fA = f2g[ks*8 + quad*2];
      float4 fB = f2g[ks*8 + quad*2 + 1];
      i32x4 aA = av[2*ks], aB = av[2*ks+1];
      float fv[8] = {fA.x, fA.y, fA.z, fA.w, fB.x, fB.y, fB.z, fB.w};
      int   ai[8] = {aA[0], aA[1], aA[2], aA[3], aB[0], aB[1], aB[2], aB[3]};
      short8 fr;
      #pragma unroll
      for (int j = 0; j < 8; ++j){
        float t = f1i + fv[j];
        float u = fmaxf(t, GAT_ALPHA * t);       // leaky relu
        float p = __builtin_amdgcn_exp2f(fmaf(u, L2E, -miL));   // exp(u-mi), <=1
        p = (ai[j] > 0) ? p : 0.f;
        lp += p;
        fr[j] = (short)f2bf(p);
      }
      afr[ks] = fr;
    }

    // 16 MFMAs: 2 K-steps x 8 col-tiles; B direct from blocked hTb (L1/L2 hit)
    const unsigned short* hkc = hb + (size_t)kc * 8192;   // + kc*128*64
    #pragma unroll
    for (int ks = 0; ks < 2; ++ks){
      #pragma unroll
      for (int ct = 0; ct < 8; ++ct){
        short8 bfr = *(const short8*)(hkc + ct * 1024 + ks * 32);
        acc[ct] = __builtin_amdgcn_mfma_f32_16x16x32_bf16(afr[ks], bfr, acc[ct], 0, 0, 0);
      }
    }

    // rotate prefetch queue: av <- bv <- nv
    #pragma unroll
    for (int q = 0; q < 4; ++q){ av[q] = bv[q]; }
    if (kc < 14){
      #pragma unroll
      for (int q = 0; q < 4; ++q){ bv[q] = nv[q]; }
    }
  }

  // ---- epilogue: per-split partial stores (plain stores -> stay in L2/L3) ----
  lp += __shfl_xor(lp, 16, 64);
  lp += __shfl_xor(lp, 32, 64);
  if (lane < 16) lpart[(size_t)s * NR + rb * 64 + w * 16 + m] = lp;

  float* op = Opart + (size_t)s * NR * DD;
  #pragma unroll
  for (int ct = 0; ct < 8; ++ct){
    int col = ct * 16 + m;
    #pragma unroll
    for (int reg = 0; reg < 4; ++reg){
      int row = rb * 64 + w * 16 + quad * 4 + reg;   // C layout: col=lane&15, row=quad*4+reg
      op[(size_t)row * DD + col] = acc[ct][reg];
    }
  }
}

// ---- k3: reduce split-K partials, out = elu(O / l) ----
__global__ __launch_bounds__(256) void k_out(
    const float* __restrict__ Opart, const float* __restrict__ lpart,
    float* __restrict__ out)
{
  const int gid = blockIdx.x * 256 + threadIdx.x;   // float4 index, 262144 total
  const int row = gid >> 5;
  float lsum = 0.f;
  float4 o = make_float4(0.f, 0.f, 0.f, 0.f);
  const float4* O4 = (const float4*)Opart;
  #pragma unroll
  for (int s = 0; s < NSPLIT; ++s){
    lsum += lpart[(size_t)s * NR + row];
    float4 v = O4[(size_t)s * (NR * DD / 4) + gid];
    o.x += v.x; o.y += v.y; o.z += v.z; o.w += v.w;
  }
  const float inv = 1.0f / lsum;
  float4 r; float x;
  x = o.x * inv; r.x = x > 0.f ? x : (__expf(x) - 1.f);
  x = o.y * inv; r.y = x > 0.f ? x : (__expf(x) - 1.f);
  x = o.z * inv; r.z = x > 0.f ? x : (__expf(x) - 1.f);
  x = o.w * inv; r.w = x > 0.f ? x : (__expf(x) - 1.f);
  ((float4*)out)[gid] = r;
}

// ---- launcher ----
extern "C" void kernel_launch(void* const* d_in, const int* in_sizes, int n_in,
                              void* d_out, int out_size, void* d_ws, size_t ws_size,
                              hipStream_t stream)
{
  const float* in  = (const float*)d_in[0];
  const int*   adj = (const int*)  d_in[1];
  const float* W   = (const float*)d_in[2];
  const float* a   = (const float*)d_in[3];
  float* out = (float*)d_out;

  char* ws = (char*)d_ws;
  // layout (bytes):
  //   gmax  [0, 4)
  //   f1    [4096,   36864)                 fp32 [8192]
  //   f2    [36864,  69632)                 fp32 [8192]
  //   hTb   [1048576, 3145728)              bf16 blocked [128][128][64]
  //   Opart [4194304, 4194304+33554432)     fp32 [8][8192][128]
  //   lpart [37748736, 38010880)            fp32 [8][8192]
  unsigned*       gmax  = (unsigned*)      (ws + 0);
  float*          f1    = (float*)         (ws + 4096);
  float*          f2    = (float*)         (ws + 36864);
  unsigned short* hTb   = (unsigned short*)(ws + 1048576);
  float*          Opart = (float*)         (ws + 4194304);
  float*          lpart = (float*)         (ws + 37748736);

  (void)hipMemsetAsync(gmax, 0, 4, stream);   // fenc-space -inf

  hipLaunchKernelGGL(k_pre,  dim3(1024),    dim3(256), 0, stream, in, W, a, hTb, f1, f2, gmax);
  hipLaunchKernelGGL(k_attn, dim3(8, 128),  dim3(256), 0, stream, adj, hTb, f1, f2, gmax, Opart, lpart);
  hipLaunchKernelGGL(k_out,  dim3(1024),    dim3(256), 0, stream, Opart, lpart, out);
}

// Round 8
// 467.985 us; speedup vs baseline: 1.1318x; 1.1318x over previous
//
#include <hip/hip_runtime.h>
#include <cstdint>
#include <cstddef>

#define NR 8192
#define DD 128
#define NSPLIT 32
#define KSPL 256               // k per split
#define GAT_ALPHA 0.2f

typedef short short8 __attribute__((ext_vector_type(8)));
typedef unsigned short ushort8 __attribute__((ext_vector_type(8)));
typedef float f32x4 __attribute__((ext_vector_type(4)));
typedef int i32x4 __attribute__((ext_vector_type(4)));

__device__ __forceinline__ unsigned short f2bf(float f){
  unsigned u = __float_as_uint(f);
  u += 0x7fffu + ((u >> 16) & 1u);           // RNE round to bf16
  return (unsigned short)(u >> 16);
}
__device__ __forceinline__ unsigned fenc(float f){   // monotone float->uint
  unsigned u = __float_as_uint(f);
  return (u & 0x80000000u) ? ~u : (u | 0x80000000u);
}
__device__ __forceinline__ float fdec(unsigned e){
  unsigned u = (e & 0x80000000u) ? (e ^ 0x80000000u) : ~e;
  return __uint_as_float(u);
}
__device__ __forceinline__ void gload_lds16(const void* g, void* l){
  __builtin_amdgcn_global_load_lds(
      (const __attribute__((address_space(1))) unsigned*)g,
      (__attribute__((address_space(3))) unsigned*)l, 16, 0, 0);
}

// ---- k1: h = in@W (regs only), f1=h@a1, f2=h@a2, gmax=max(f2), hT=bf16(h)^T
__global__ __launch_bounds__(256) void k_pre(
    const float* __restrict__ in, const float* __restrict__ W,
    const float* __restrict__ a,
    unsigned short* __restrict__ hT, float* __restrict__ f1,
    float* __restrict__ f2, unsigned* __restrict__ gmax)
{
  __shared__ __align__(16) unsigned short sT[128][8];   // [col][row-in-block]
  const int tid = threadIdx.x;
  const int g = blockIdx.x * 256 + tid;
  const int r  = g >> 5;                    // row 0..8191 (8 rows per block)
  const int cg = g & 31;                    // col-quad
  const float4* inr = (const float4*)(in + (size_t)r * DD);
  const float4* W4  = (const float4*)W;
  float4 acc = make_float4(0.f, 0.f, 0.f, 0.f);
  #pragma unroll 4
  for (int k4 = 0; k4 < 32; ++k4){
    float4 iv = inr[k4];
    float4 wv;
    wv = W4[(k4*4+0)*32 + cg];
    acc.x = fmaf(iv.x, wv.x, acc.x); acc.y = fmaf(iv.x, wv.y, acc.y);
    acc.z = fmaf(iv.x, wv.z, acc.z); acc.w = fmaf(iv.x, wv.w, acc.w);
    wv = W4[(k4*4+1)*32 + cg];
    acc.x = fmaf(iv.y, wv.x, acc.x); acc.y = fmaf(iv.y, wv.y, acc.y);
    acc.z = fmaf(iv.y, wv.z, acc.z); acc.w = fmaf(iv.y, wv.w, acc.w);
    wv = W4[(k4*4+2)*32 + cg];
    acc.x = fmaf(iv.z, wv.x, acc.x); acc.y = fmaf(iv.z, wv.y, acc.y);
    acc.z = fmaf(iv.z, wv.z, acc.z); acc.w = fmaf(iv.z, wv.w, acc.w);
    wv = W4[(k4*4+3)*32 + cg];
    acc.x = fmaf(iv.w, wv.x, acc.x); acc.y = fmaf(iv.w, wv.y, acc.y);
    acc.z = fmaf(iv.w, wv.z, acc.z); acc.w = fmaf(iv.w, wv.w, acc.w);
  }
  const int c0 = cg * 4;
  float s1 = acc.x*a[c0] + acc.y*a[c0+1] + acc.z*a[c0+2] + acc.w*a[c0+3];
  float s2 = acc.x*a[128+c0] + acc.y*a[128+c0+1] + acc.z*a[128+c0+2] + acc.w*a[128+c0+3];
  #pragma unroll
  for (int off = 16; off; off >>= 1){
    s1 += __shfl_xor(s1, off, 64);
    s2 += __shfl_xor(s2, off, 64);
  }
  if ((tid & 31) == 0){
    f1[r] = s1; f2[r] = s2;
    atomicMax(gmax, fenc(s2));
  }
  const int rl = r & 7;
  sT[c0+0][rl] = f2bf(acc.x);
  sT[c0+1][rl] = f2bf(acc.y);
  sT[c0+2][rl] = f2bf(acc.z);
  sT[c0+3][rl] = f2bf(acc.w);
  __syncthreads();
  if (tid < 128){
    ushort8 v = *(const ushort8*)&sT[tid][0];
    *(ushort8*)(hT + (size_t)tid * NR + blockIdx.x * 8) = v;
  }
}

// ---- k2: masked-softmax-weighted GEMM — one-shot LDS staging, barrier-free K-loop
// grid (32 ksplits, 64 rowblocks) x 512 thr (8 waves); wave owns 16 rows x 128 cols.
// B-slice (256k x 128c = 64KB) staged ONCE via global_load_lds; then 4 fully
// unrolled 64-k chunks with NO barriers: adj on vmcnt (depth-2 prefetch),
// B on lgkmcnt (ds_read) — the two streams never drain each other.
__global__ __launch_bounds__(512, 4) void k_attn(
    const int* __restrict__ adj, const unsigned short* __restrict__ hT,
    const float* __restrict__ f1, const float* __restrict__ f2,
    const unsigned* __restrict__ gmax,
    float* __restrict__ Opart, float* __restrict__ lpart)
{
  const int s    = blockIdx.x;        // ksplit 0..31  (256 k each, 4 chunks)
  const int rb   = blockIdx.y;        // rowblock 0..63 (128 rows)
  const int tid  = threadIdx.x;
  const int w    = tid >> 6;          // wave 0..7
  const int lane = tid & 63;
  const int quad = lane >> 4;
  const int m    = lane & 15;
  const int i    = rb * 128 + w * 16 + m;   // this lane's P row
  const int k0   = s * KSPL;

  __shared__ float4 sHT[4096];        // exactly 64KB: 128 cols x 32 k-octets, XOR swizzled

  const float F2MAX = fdec(*gmax);
  const float f1i = f1[i];
  const float mm = f1i + F2MAX;
  const float mi = fmaxf(mm, GAT_ALPHA * mm);  // lrelu(f1+maxf2) >= row max, exact bound
  const float L2E = 1.44269504089f;
  const float miL = mi * L2E;

  f32x4 acc[8];
  #pragma unroll
  for (int ct = 0; ct < 8; ++ct){ acc[ct][0]=0.f; acc[ct][1]=0.f; acc[ct][2]=0.f; acc[ct][3]=0.f; }
  float lp = 0.f;

  const int* arow = adj + (size_t)i * NR + k0 + quad * 8;

  i32x4 av[4], bv[4], nv[4];          // depth-2 rotating adj prefetch queue

  auto loadAdj = [&](int kc, i32x4* dst){
    const i32x4* p0 = (const i32x4*)(arow + kc * 64);
    #pragma unroll
    for (int ks = 0; ks < 2; ++ks){
      dst[2*ks]   = __builtin_nontemporal_load(p0 + ks*8);
      dst[2*ks+1] = __builtin_nontemporal_load(p0 + ks*8 + 1);
    }
  };

  // ---- one-shot staging of the whole 256-k B slice (64KB) ----
  #pragma unroll
  for (int q = 0; q < 8; ++q){
    int lin  = q * 512 + tid;         // 16B block index 0..4095
    int c    = lin >> 5;              // feature col 0..127
    int blk  = lin & 31;              // k-octet within split
    int sblk = (blk & ~7) | ((blk & 7) ^ (c & 7));   // XOR swizzle (low 3 bits)
    gload_lds16(hT + (size_t)c * NR + k0 + (size_t)sblk * 8, &sHT[lin]);
  }
  loadAdj(0, av);
  loadAdj(1, bv);
  __syncthreads();                    // the ONLY barrier

  #pragma unroll
  for (int kc = 0; kc < 4; ++kc){
    // f2 loads FIRST (so waiting on them leaves newest adj prefetch in flight)
    const float4* f2g = (const float4*)(f2 + k0 + kc * 64);
    float4 fA0 = f2g[quad*2],      fB0 = f2g[quad*2 + 1];
    float4 fA1 = f2g[8 + quad*2],  fB1 = f2g[8 + quad*2 + 1];

    if (kc < 2) loadAdj(kc + 2, nv);  // depth-2 register prefetch (vmcnt stream)

    // P in A-frag layout: A[m=lane&15][k = ks*32 + quad*8 + j]
    short8 afr[2];
    #pragma unroll
    for (int ks = 0; ks < 2; ++ks){
      float4 fA = ks ? fA1 : fA0;
      float4 fB = ks ? fB1 : fB0;
      i32x4 aA = av[2*ks], aB = av[2*ks+1];
      float fv[8] = {fA.x, fA.y, fA.z, fA.w, fB.x, fB.y, fB.z, fB.w};
      int   ai[8] = {aA[0], aA[1], aA[2], aA[3], aB[0], aB[1], aB[2], aB[3]};
      short8 fr;
      #pragma unroll
      for (int j = 0; j < 8; ++j){
        float t = f1i + fv[j];
        float u = fmaxf(t, GAT_ALPHA * t);       // leaky relu
        float p = __builtin_amdgcn_exp2f(fmaf(u, L2E, -miL));   // exp(u-mi), <=1
        p = (ai[j] > 0) ? p : 0.f;
        lp += p;
        fr[j] = (short)f2bf(p);
      }
      afr[ks] = fr;
    }

    // 16 MFMAs: 2 K-steps x 8 col-tiles; B via ds_read_b128 (lgkmcnt only)
    const short8* sB = (const short8*)&sHT[0];
    #pragma unroll
    for (int ks = 0; ks < 2; ++ks){
      #pragma unroll
      for (int ct = 0; ct < 8; ++ct){
        int c = ct * 16 + m;
        int o = kc * 8 + ks * 4 + quad;          // k-octet within split 0..31
        int so = (o & ~7) | ((o & 7) ^ (c & 7));
        short8 bfr = sB[c * 32 + so];
        acc[ct] = __builtin_amdgcn_mfma_f32_16x16x32_bf16(afr[ks], bfr, acc[ct], 0, 0, 0);
      }
    }

    // rotate prefetch queue: av <- bv <- nv
    #pragma unroll
    for (int q = 0; q < 4; ++q){ av[q] = bv[q]; }
    if (kc < 2){
      #pragma unroll
      for (int q = 0; q < 4; ++q){ bv[q] = nv[q]; }
    }
  }

  // ---- epilogue: per-split partial stores (plain stores -> stay in L2/L3) ----
  lp += __shfl_xor(lp, 16, 64);
  lp += __shfl_xor(lp, 32, 64);
  if (lane < 16) lpart[(size_t)s * NR + rb * 128 + w * 16 + m] = lp;

  float* op = Opart + (size_t)s * NR * DD;
  #pragma unroll
  for (int ct = 0; ct < 8; ++ct){
    int col = ct * 16 + m;
    #pragma unroll
    for (int reg = 0; reg < 4; ++reg){
      int row = rb * 128 + w * 16 + quad * 4 + reg;  // C layout: col=lane&15, row=quad*4+reg
      op[(size_t)row * DD + col] = acc[ct][reg];
    }
  }
}

// ---- k3: reduce split-K partials, out = elu(O / l) ----
__global__ __launch_bounds__(256) void k_out(
    const float* __restrict__ Opart, const float* __restrict__ lpart,
    float* __restrict__ out)
{
  const int gid = blockIdx.x * 256 + threadIdx.x;   // float4 index, 262144 total
  const int row = gid >> 5;
  float lsum = 0.f;
  float4 o = make_float4(0.f, 0.f, 0.f, 0.f);
  const float4* O4 = (const float4*)Opart;
  #pragma unroll 8
  for (int s = 0; s < NSPLIT; ++s){
    lsum += lpart[(size_t)s * NR + row];
    float4 v = O4[(size_t)s * (NR * DD / 4) + gid];
    o.x += v.x; o.y += v.y; o.z += v.z; o.w += v.w;
  }
  const float inv = 1.0f / lsum;
  float4 r; float x;
  x = o.x * inv; r.x = x > 0.f ? x : (__expf(x) - 1.f);
  x = o.y * inv; r.y = x > 0.f ? x : (__expf(x) - 1.f);
  x = o.z * inv; r.z = x > 0.f ? x : (__expf(x) - 1.f);
  x = o.w * inv; r.w = x > 0.f ? x : (__expf(x) - 1.f);
  ((float4*)out)[gid] = r;
}

// ---- launcher ----
extern "C" void kernel_launch(void* const* d_in, const int* in_sizes, int n_in,
                              void* d_out, int out_size, void* d_ws, size_t ws_size,
                              hipStream_t stream)
{
  const float* in  = (const float*)d_in[0];
  const int*   adj = (const int*)  d_in[1];
  const float* W   = (const float*)d_in[2];
  const float* a   = (const float*)d_in[3];
  float* out = (float*)d_out;

  char* ws = (char*)d_ws;
  // layout (bytes):
  //   gmax  [0, 4)
  //   f1    [4096,   36864)                  fp32 [8192]
  //   f2    [36864,  69632)                  fp32 [8192]
  //   hT    [1048576, 3145728)               bf16 [128][8192]
  //   Opart [4194304, 138412032)             fp32 [32][8192][128]
  //   lpart [138412032, 139460608)           fp32 [32][8192]
  unsigned*       gmax  = (unsigned*)      (ws + 0);
  float*          f1    = (float*)         (ws + 4096);
  float*          f2    = (float*)         (ws + 36864);
  unsigned short* hT    = (unsigned short*)(ws + 1048576);
  float*          Opart = (float*)         (ws + 4194304);
  float*          lpart = (float*)         (ws + 138412032);

  (void)hipMemsetAsync(gmax, 0, 4, stream);   // fenc-space -inf

  hipLaunchKernelGGL(k_pre,  dim3(1024),    dim3(256), 0, stream, in, W, a, hT, f1, f2, gmax);
  hipLaunchKernelGGL(k_attn, dim3(32, 64),  dim3(512), 0, stream, adj, hT, f1, f2, gmax, Opart, lpart);
  hipLaunchKernelGGL(k_out,  dim3(1024),    dim3(256), 0, stream, Opart, lpart, out);
}

// Round 9
// 461.508 us; speedup vs baseline: 1.1476x; 1.0140x over previous
//
#include <hip/hip_runtime.h>
#include <cstdint>
#include <cstddef>

#define NR 8192
#define DD 128
#define NSPLIT 32
#define KSPL 256               // k per split
#define GAT_ALPHA 0.2f

typedef short short8 __attribute__((ext_vector_type(8)));
typedef unsigned short ushort8 __attribute__((ext_vector_type(8)));
typedef float f32x4 __attribute__((ext_vector_type(4)));
typedef int i32x4 __attribute__((ext_vector_type(4)));

__device__ __forceinline__ unsigned short f2bf(float f){
  unsigned u = __float_as_uint(f);
  u += 0x7fffu + ((u >> 16) & 1u);           // RNE round to bf16
  return (unsigned short)(u >> 16);
}
__device__ __forceinline__ unsigned fenc(float f){   // monotone float->uint
  unsigned u = __float_as_uint(f);
  return (u & 0x80000000u) ? ~u : (u | 0x80000000u);
}
__device__ __forceinline__ float fdec(unsigned e){
  unsigned u = (e & 0x80000000u) ? (e ^ 0x80000000u) : ~e;
  return __uint_as_float(u);
}
__device__ __forceinline__ void gload_lds16(const void* g, void* l){
  __builtin_amdgcn_global_load_lds(
      (const __attribute__((address_space(1))) unsigned*)g,
      (__attribute__((address_space(3))) unsigned*)l, 16, 0, 0);
}

// ---- k1: h = in@W (regs only), f1=h@a1, f2=h@a2, gmax=max(f2), hT=bf16(h)^T
__global__ __launch_bounds__(256) void k_pre(
    const float* __restrict__ in, const float* __restrict__ W,
    const float* __restrict__ a,
    unsigned short* __restrict__ hT, float* __restrict__ f1,
    float* __restrict__ f2, unsigned* __restrict__ gmax)
{
  __shared__ __align__(16) unsigned short sT[128][8];   // [col][row-in-block]
  const int tid = threadIdx.x;
  const int g = blockIdx.x * 256 + tid;
  const int r  = g >> 5;                    // row 0..8191 (8 rows per block)
  const int cg = g & 31;                    // col-quad
  const float4* inr = (const float4*)(in + (size_t)r * DD);
  const float4* W4  = (const float4*)W;
  float4 acc = make_float4(0.f, 0.f, 0.f, 0.f);
  #pragma unroll 4
  for (int k4 = 0; k4 < 32; ++k4){
    float4 iv = inr[k4];
    float4 wv;
    wv = W4[(k4*4+0)*32 + cg];
    acc.x = fmaf(iv.x, wv.x, acc.x); acc.y = fmaf(iv.x, wv.y, acc.y);
    acc.z = fmaf(iv.x, wv.z, acc.z); acc.w = fmaf(iv.x, wv.w, acc.w);
    wv = W4[(k4*4+1)*32 + cg];
    acc.x = fmaf(iv.y, wv.x, acc.x); acc.y = fmaf(iv.y, wv.y, acc.y);
    acc.z = fmaf(iv.y, wv.z, acc.z); acc.w = fmaf(iv.y, wv.w, acc.w);
    wv = W4[(k4*4+2)*32 + cg];
    acc.x = fmaf(iv.z, wv.x, acc.x); acc.y = fmaf(iv.z, wv.y, acc.y);
    acc.z = fmaf(iv.z, wv.z, acc.z); acc.w = fmaf(iv.z, wv.w, acc.w);
    wv = W4[(k4*4+3)*32 + cg];
    acc.x = fmaf(iv.w, wv.x, acc.x); acc.y = fmaf(iv.w, wv.y, acc.y);
    acc.z = fmaf(iv.w, wv.z, acc.z); acc.w = fmaf(iv.w, wv.w, acc.w);
  }
  const int c0 = cg * 4;
  float s1 = acc.x*a[c0] + acc.y*a[c0+1] + acc.z*a[c0+2] + acc.w*a[c0+3];
  float s2 = acc.x*a[128+c0] + acc.y*a[128+c0+1] + acc.z*a[128+c0+2] + acc.w*a[128+c0+3];
  #pragma unroll
  for (int off = 16; off; off >>= 1){
    s1 += __shfl_xor(s1, off, 64);
    s2 += __shfl_xor(s2, off, 64);
  }
  if ((tid & 31) == 0){
    f1[r] = s1; f2[r] = s2;
    atomicMax(gmax, fenc(s2));
  }
  const int rl = r & 7;
  sT[c0+0][rl] = f2bf(acc.x);
  sT[c0+1][rl] = f2bf(acc.y);
  sT[c0+2][rl] = f2bf(acc.z);
  sT[c0+3][rl] = f2bf(acc.w);
  __syncthreads();
  if (tid < 128){
    ushort8 v = *(const ushort8*)&sT[tid][0];
    *(ushort8*)(hT + (size_t)tid * NR + blockIdx.x * 8) = v;
  }
}

// ---- k2: masked-softmax-weighted GEMM — zero in-loop global loads ---------
// grid (32 ksplits, 64 rowblocks) x 512 thr (8 waves); wave owns 16 rows x 128 cols.
// Prologue: ALL adj for the split (depth-4, 64 VGPR/lane) + hT slice (64KB) +
// f2 slice (1KB) loaded in one deep burst; ONE barrier; then a K-loop that
// touches only registers and LDS.
__global__ __launch_bounds__(512, 4) void k_attn(
    const int* __restrict__ adj, const unsigned short* __restrict__ hT,
    const float* __restrict__ f1, const float* __restrict__ f2,
    const unsigned* __restrict__ gmax,
    float* __restrict__ Opart, float* __restrict__ lpart)
{
  const int s    = blockIdx.x;        // ksplit 0..31  (256 k each, 4 chunks)
  const int rb   = blockIdx.y;        // rowblock 0..63 (128 rows)
  const int tid  = threadIdx.x;
  const int w    = tid >> 6;          // wave 0..7
  const int lane = tid & 63;
  const int quad = lane >> 4;
  const int m    = lane & 15;
  const int i    = rb * 128 + w * 16 + m;   // this lane's P row
  const int k0   = s * KSPL;

  __shared__ float4 sHT[4096];        // 64KB: 128 cols x 32 k-octets, XOR swizzled
  __shared__ __align__(16) float sF2[KSPL];   // 1KB: f2 slice for this split

  const float F2MAX = fdec(*gmax);
  const float f1i = f1[i];
  const float mm = f1i + F2MAX;
  const float mi = fmaxf(mm, GAT_ALPHA * mm);  // lrelu(f1+maxf2) >= row max, exact bound
  const float L2E = 1.44269504089f;
  const float miL = mi * L2E;

  f32x4 acc[8];
  #pragma unroll
  for (int ct = 0; ct < 8; ++ct){ acc[ct][0]=0.f; acc[ct][1]=0.f; acc[ct][2]=0.f; acc[ct][3]=0.f; }
  float lp = 0.f;

  const int* arow = adj + (size_t)i * NR + k0 + quad * 8;

  // ---- prologue: one deep burst of everything ----
  i32x4 av[16];                       // ALL adj for the split: 4 chunks x 64B/lane
  #pragma unroll
  for (int kc = 0; kc < 4; ++kc){
    const i32x4* p0 = (const i32x4*)(arow + kc * 64);
    av[4*kc+0] = __builtin_nontemporal_load(p0);
    av[4*kc+1] = __builtin_nontemporal_load(p0 + 1);
    av[4*kc+2] = __builtin_nontemporal_load(p0 + 8);
    av[4*kc+3] = __builtin_nontemporal_load(p0 + 9);
  }
  #pragma unroll
  for (int q = 0; q < 8; ++q){
    int lin  = q * 512 + tid;         // 16B block index 0..4095
    int c    = lin >> 5;              // feature col 0..127
    int blk  = lin & 31;              // k-octet within split
    int sblk = (blk & ~7) | ((blk & 7) ^ (c & 7));   // XOR swizzle (low 3 bits)
    gload_lds16(hT + (size_t)c * NR + k0 + (size_t)sblk * 8, &sHT[lin]);
  }
  if (tid < 64) ((float4*)sF2)[tid] = ((const float4*)(f2 + k0))[tid];
  __syncthreads();                    // the ONLY barrier

  #pragma unroll
  for (int kc = 0; kc < 4; ++kc){
    // P in A-frag layout: A[m=lane&15][k = ks*32 + quad*8 + j]; f2 via LDS
    const float4* f2v = (const float4*)sF2 + kc * 16;
    short8 afr[2];
    #pragma unroll
    for (int ks = 0; ks < 2; ++ks){
      float4 fA = f2v[ks*8 + quad*2];
      float4 fB = f2v[ks*8 + quad*2 + 1];
      i32x4 aA = av[4*kc + 2*ks], aB = av[4*kc + 2*ks + 1];
      float fv[8] = {fA.x, fA.y, fA.z, fA.w, fB.x, fB.y, fB.z, fB.w};
      int   ai[8] = {aA[0], aA[1], aA[2], aA[3], aB[0], aB[1], aB[2], aB[3]};
      short8 fr;
      #pragma unroll
      for (int j = 0; j < 8; ++j){
        float t = f1i + fv[j];
        float u = fmaxf(t, GAT_ALPHA * t);       // leaky relu
        float p = __builtin_amdgcn_exp2f(fmaf(u, L2E, -miL));   // exp(u-mi), <=1
        p = (ai[j] > 0) ? p : 0.f;
        lp += p;
        fr[j] = (short)f2bf(p);
      }
      afr[ks] = fr;
    }

    // 16 MFMAs: 2 K-steps x 8 col-tiles; B via ds_read_b128 (lgkmcnt only)
    const short8* sB = (const short8*)&sHT[0];
    #pragma unroll
    for (int ks = 0; ks < 2; ++ks){
      #pragma unroll
      for (int ct = 0; ct < 8; ++ct){
        int c = ct * 16 + m;
        int o = kc * 8 + ks * 4 + quad;          // k-octet within split 0..31
        int so = (o & ~7) | ((o & 7) ^ (c & 7));
        short8 bfr = sB[c * 32 + so];
        acc[ct] = __builtin_amdgcn_mfma_f32_16x16x32_bf16(afr[ks], bfr, acc[ct], 0, 0, 0);
      }
    }
  }

  // ---- epilogue: per-split partial stores (plain stores -> stay in L2/L3) ----
  lp += __shfl_xor(lp, 16, 64);
  lp += __shfl_xor(lp, 32, 64);
  if (lane < 16) lpart[(size_t)s * NR + rb * 128 + w * 16 + m] = lp;

  float* op = Opart + (size_t)s * NR * DD;
  #pragma unroll
  for (int ct = 0; ct < 8; ++ct){
    int col = ct * 16 + m;
    #pragma unroll
    for (int reg = 0; reg < 4; ++reg){
      int row = rb * 128 + w * 16 + quad * 4 + reg;  // C layout: col=lane&15, row=quad*4+reg
      op[(size_t)row * DD + col] = acc[ct][reg];
    }
  }
}

// ---- k3: reduce split-K partials, out = elu(O / l) ----
__global__ __launch_bounds__(256) void k_out(
    const float* __restrict__ Opart, const float* __restrict__ lpart,
    float* __restrict__ out)
{
  const int gid = blockIdx.x * 256 + threadIdx.x;   // float4 index, 262144 total
  const int row = gid >> 5;
  float lsum = 0.f;
  float4 o = make_float4(0.f, 0.f, 0.f, 0.f);
  const float4* O4 = (const float4*)Opart;
  #pragma unroll 8
  for (int s = 0; s < NSPLIT; ++s){
    lsum += lpart[(size_t)s * NR + row];
    float4 v = O4[(size_t)s * (NR * DD / 4) + gid];
    o.x += v.x; o.y += v.y; o.z += v.z; o.w += v.w;
  }
  const float inv = 1.0f / lsum;
  float4 r; float x;
  x = o.x * inv; r.x = x > 0.f ? x : (__expf(x) - 1.f);
  x = o.y * inv; r.y = x > 0.f ? x : (__expf(x) - 1.f);
  x = o.z * inv; r.z = x > 0.f ? x : (__expf(x) - 1.f);
  x = o.w * inv; r.w = x > 0.f ? x : (__expf(x) - 1.f);
  ((float4*)out)[gid] = r;
}

// ---- launcher ----
extern "C" void kernel_launch(void* const* d_in, const int* in_sizes, int n_in,
                              void* d_out, int out_size, void* d_ws, size_t ws_size,
                              hipStream_t stream)
{
  const float* in  = (const float*)d_in[0];
  const int*   adj = (const int*)  d_in[1];
  const float* W   = (const float*)d_in[2];
  const float* a   = (const float*)d_in[3];
  float* out = (float*)d_out;

  char* ws = (char*)d_ws;
  // layout (bytes):
  //   gmax  [0, 4)
  //   f1    [4096,   36864)                  fp32 [8192]
  //   f2    [36864,  69632)                  fp32 [8192]
  //   hT    [1048576, 3145728)               bf16 [128][8192]
  //   Opart [4194304, 138412032)             fp32 [32][8192][128]
  //   lpart [138412032, 139460608)           fp32 [32][8192]
  unsigned*       gmax  = (unsigned*)      (ws + 0);
  float*          f1    = (float*)         (ws + 4096);
  float*          f2    = (float*)         (ws + 36864);
  unsigned short* hT    = (unsigned short*)(ws + 1048576);
  float*          Opart = (float*)         (ws + 4194304);
  float*          lpart = (float*)         (ws + 138412032);

  (void)hipMemsetAsync(gmax, 0, 4, stream);   // fenc-space -inf

  hipLaunchKernelGGL(k_pre,  dim3(1024),    dim3(256), 0, stream, in, W, a, hT, f1, f2, gmax);
  hipLaunchKernelGGL(k_attn, dim3(32, 64),  dim3(512), 0, stream, adj, hT, f1, f2, gmax, Opart, lpart);
  hipLaunchKernelGGL(k_out,  dim3(1024),    dim3(256), 0, stream, Opart, lpart, out);
}